// Round 6
// baseline (332.657 us; speedup 1.0000x reference)
//
#include <hip/hip_runtime.h>
#include <hip/hip_bf16.h>

#define N_NODES 50000
#define HID     256
#define N_EDGES 300000
#define NT      32   // nodes per GEMM tile
#define NTILES  ((N_NODES + NT - 1) / NT)
#define H_NODE  25000   // node-set split for edge classes

typedef __attribute__((ext_vector_type(8))) short bf16x8;
typedef __attribute__((ext_vector_type(4))) float f32x4;

__device__ __forceinline__ unsigned short f2bf(float f) {
  unsigned int u = __float_as_uint(f);
  u = (u + 0x7FFFu + ((u >> 16) & 1u)) >> 16;   // RNE
  return (unsigned short)u;
}
__device__ __forceinline__ float bflo(unsigned int u) { return __uint_as_float(u << 16); }
__device__ __forceinline__ float bfhi(unsigned int u) { return __uint_as_float(u & 0xFFFF0000u); }

__device__ __forceinline__ bf16x8 cvt8(float4 u, float4 v) {
  bf16x8 r;
  r[0] = (short)f2bf(u.x); r[1] = (short)f2bf(u.y);
  r[2] = (short)f2bf(u.z); r[3] = (short)f2bf(u.w);
  r[4] = (short)f2bf(v.x); r[5] = (short)f2bf(v.y);
  r[6] = (short)f2bf(v.z); r[7] = (short)f2bf(v.w);
  return r;
}

struct StageRegs { float4 a, b, c, d; };

__device__ __forceinline__ void load_tile(const float* __restrict__ E, int tile,
                                          int srow, int sg, StageRegs& s) {
  int grow = tile * NT + srow;
  if (grow < N_NODES) {
    const float4* p = reinterpret_cast<const float4*>(E + (size_t)grow * HID + sg * 8);
    s.a = p[0]; s.b = p[1]; s.c = p[32]; s.d = p[33];
  } else {
    s.a = s.b = s.c = s.d = make_float4(0.f, 0.f, 0.f, 0.f);
  }
}

// ---- kernel 1: Wcat^T in MFMA-fragment order; also zeros the edge-class ctl block.
__global__ __launch_bounds__(128) void pack_w_kernel(
    const float* __restrict__ W1, unsigned short* __restrict__ Wtf, int* __restrict__ ctl) {
  if (blockIdx.x == 0 && threadIdx.x < 12) ctl[threadIdx.x] = 0;
  int k = blockIdx.x;          // 0..255
  int t = threadIdx.x;         // 0..127
  int half = t >> 6;
  int jj = (t & 63) * 4;
  const float4 v = *reinterpret_cast<const float4*>(
      W1 + (size_t)(half ? (HID + k) : k) * HID + jj);
  float vv[4] = {v.x, v.y, v.z, v.w};
#pragma unroll
  for (int e = 0; e < 4; ++e) {
    int j = half * HID + jj + e;
    int f    = (j >> 4) * 8 + (k >> 5);
    int lane = (j & 15) | (((k >> 3) & 3) << 4);
    int elem = k & 7;
    Wtf[f * 512 + lane * 8 + elem] = f2bf(vv[e]);
  }
}

// ---- edge-class bucketing: ctl[0..3]=cnt, ctl[4..7]=cursor, ctl[8..11]=base
__global__ __launch_bounds__(256) void hist_kernel(const int* __restrict__ idx,
                                                   int* __restrict__ ctl) {
  __shared__ int h[4];
  if (threadIdx.x < 4) h[threadIdx.x] = 0;
  __syncthreads();
  int stride = gridDim.x * blockDim.x;
  for (int e = blockIdx.x * blockDim.x + threadIdx.x; e < N_EDGES; e += stride) {
    int s = idx[e], t = idx[N_EDGES + e];
    int c = ((s >= H_NODE) << 1) | (t >= H_NODE);
    atomicAdd(&h[c], 1);
  }
  __syncthreads();
  if (threadIdx.x < 4) atomicAdd(&ctl[threadIdx.x], h[threadIdx.x]);
}

__global__ void scan_kernel(int* __restrict__ ctl) {
  if (threadIdx.x == 0 && blockIdx.x == 0) {
    int run = 0;
#pragma unroll
    for (int c = 0; c < 4; ++c) {
      ctl[8 + c] = run;     // base
      ctl[4 + c] = run;     // cursor starts at base
      run += ctl[c];
    }
  }
}

__global__ __launch_bounds__(256) void scatter_kernel(const int* __restrict__ idx,
                                                      int* __restrict__ ctl,
                                                      int* __restrict__ perm) {
  const int lane = threadIdx.x & 63;
  int stride = gridDim.x * blockDim.x;
  for (int e = blockIdx.x * blockDim.x + threadIdx.x; ; e += stride) {
    bool valid = e < N_EDGES;
    if (!__ballot(valid)) break;   // whole wave done
    int c = 0;
    if (valid) {
      int s = idx[e], t = idx[N_EDGES + e];
      c = ((s >= H_NODE) << 1) | (t >= H_NODE);
    }
#pragma unroll
    for (int cc = 0; cc < 4; ++cc) {
      unsigned long long m = __ballot(valid && c == cc);
      if (m == 0ull) continue;                    // wave-uniform
      int leader = __ffsll((unsigned long long)m) - 1;
      int nsel = __popcll(m);
      int pos0 = 0;
      if (lane == leader) pos0 = atomicAdd(&ctl[4 + cc], nsel);
      pos0 = __shfl(pos0, leader, 64);
      if (valid && c == cc) {
        int rank = __popcll(m & ((1ull << lane) - 1ull));
        perm[pos0 + rank] = e;
      }
    }
  }
}

// ---- kernel 2: weights-stationary streaming GEMM, depth-2 prefetch.
__global__ __launch_bounds__(512, 2) void gemm_kernel(
    const float* __restrict__ E, const unsigned short* __restrict__ Wtf,
    const float* __restrict__ b1, unsigned short* __restrict__ P) {
  __shared__ alignas(16) char lds0[16384];   // 32 rows x 512B bf16, XOR-swizzled
  __shared__ alignas(16) char lds1[16384];
  const int tid  = threadIdx.x;
  const int lane = tid & 63;
  const int w    = tid >> 6;                 // 0..7

  bf16x8 a[4][8];
#pragma unroll
  for (int m = 0; m < 4; ++m)
#pragma unroll
    for (int kk = 0; kk < 8; ++kk)
      a[m][kk] = *reinterpret_cast<const bf16x8*>(
          Wtf + (((size_t)(w * 4 + m) * 8 + kk) << 9) + lane * 8);

  float4 bv[4];
#pragma unroll
  for (int m = 0; m < 4; ++m) {
    int fm = w * 4 + m;
    bv[m] = (fm < 16) ? *reinterpret_cast<const float4*>(b1 + fm * 16 + ((lane >> 4) << 2))
                      : make_float4(0.f, 0.f, 0.f, 0.f);
  }

  const int srow = tid >> 4;               // 0..31
  const int sg   = tid & 15;
  const int woff0 = srow * 512 + ((sg * 16) ^ ((srow & 7) << 4));
  const int woff1 = srow * 512 + (((sg + 16) * 16) ^ ((srow & 7) << 4));
  const int G = gridDim.x;

  auto write_tile = [&](char* buf, const StageRegs& s) {
    *reinterpret_cast<bf16x8*>(&buf[woff0]) = cvt8(s.a, s.b);
    *reinterpret_cast<bf16x8*>(&buf[woff1]) = cvt8(s.c, s.d);
  };

  auto compute_store = [&](const char* buf, int tt) {
    f32x4 acc[4][2] = {};
#pragma unroll
    for (int n = 0; n < 2; ++n) {
      int r   = n * 16 + (lane & 15);
      int rb  = r * 512;
      int sw  = (r & 7) << 4;
      int kb0 = (lane >> 4) << 4;
      bf16x8 bfr[8];
#pragma unroll
      for (int kk = 0; kk < 8; ++kk)
        bfr[kk] = *reinterpret_cast<const bf16x8*>(&buf[rb + ((kk * 64 + kb0) ^ sw)]);
#pragma unroll
      for (int kk = 0; kk < 8; ++kk)
#pragma unroll
        for (int m = 0; m < 4; ++m)
          acc[m][n] = __builtin_amdgcn_mfma_f32_16x16x32_bf16(a[m][kk], bfr[kk], acc[m][n], 0, 0, 0);
    }
#pragma unroll
    for (int m = 0; m < 4; ++m) {
      int pcb = (w * 4 + m) * 16 + ((lane >> 4) << 2);
#pragma unroll
      for (int n = 0; n < 2; ++n) {
        int node = tt * NT + n * 16 + (lane & 15);
        if (node < N_NODES) {
          ushort4 o;
          o.x = f2bf(acc[m][n][0] + bv[m].x);
          o.y = f2bf(acc[m][n][1] + bv[m].y);
          o.z = f2bf(acc[m][n][2] + bv[m].z);
          o.w = f2bf(acc[m][n][3] + bv[m].w);
          *reinterpret_cast<ushort4*>(P + (size_t)node * 512 + pcb) = o;
        }
      }
    }
  };

  int t = blockIdx.x;
  StageRegs sX, sY;
  load_tile(E, t, srow, sg, sX);
  if (t + G < NTILES) load_tile(E, t + G, srow, sg, sY);
  write_tile(lds0, sX);
  if (t + 2 * G < NTILES) load_tile(E, t + 2 * G, srow, sg, sX);
  __syncthreads();

  while (true) {
    compute_store(lds0, t);
    if (t + G >= NTILES) break;
    write_tile(lds1, sY);
    if (t + 3 * G < NTILES) load_tile(E, t + 3 * G, srow, sg, sY);
    __syncthreads();
    t += G;
    compute_store(lds1, t);
    if (t + G >= NTILES) break;
    write_tile(lds0, sX);
    if (t + 3 * G < NTILES) load_tile(E, t + 3 * G, srow, sg, sX);
    __syncthreads();
    t += G;
  }
}

// ---- kernel 3: per class, 1 edge per 32-lane half, via perm indirection.
__global__ __launch_bounds__(256) void edge_kernel(
    const int* __restrict__ idx, const int* __restrict__ perm,
    const int* __restrict__ ctl, int cls,
    const unsigned short* __restrict__ P,
    const float* __restrict__ W2, const float* __restrict__ b2,
    float* __restrict__ out) {
  const int tid  = threadIdx.x;
  const int lane = tid & 63;
  const int l32  = lane & 31;
  const int half = lane >> 5;
  const int start = ctl[8 + cls];
  const int count = ctl[cls];
  const int hw = (blockIdx.x * 4 + (tid >> 6)) * 2 + half;   // global half id
  const int nh = gridDim.x * 8;
  const float4 w0 = *reinterpret_cast<const float4*>(W2 + l32 * 8);
  const float4 w1 = *reinterpret_cast<const float4*>(W2 + l32 * 8 + 4);
  const float bias = b2[0];
  for (int i = hw; i < count; i += nh) {
    int e = perm[start + i];
    int s = idx[e];
    int t = idx[N_EDGES + e];
    uint4 ua = *reinterpret_cast<const uint4*>(P + (size_t)s * 512 + l32 * 8);
    uint4 ub = *reinterpret_cast<const uint4*>(P + (size_t)t * 512 + 256 + l32 * 8);
    float h0 = fmaxf(bflo(ua.x) + bflo(ub.x), 0.f);
    float h1 = fmaxf(bfhi(ua.x) + bfhi(ub.x), 0.f);
    float h2 = fmaxf(bflo(ua.y) + bflo(ub.y), 0.f);
    float h3 = fmaxf(bfhi(ua.y) + bfhi(ub.y), 0.f);
    float h4 = fmaxf(bflo(ua.z) + bflo(ub.z), 0.f);
    float h5 = fmaxf(bfhi(ua.z) + bfhi(ub.z), 0.f);
    float h6 = fmaxf(bflo(ua.w) + bflo(ub.w), 0.f);
    float h7 = fmaxf(bfhi(ua.w) + bfhi(ub.w), 0.f);
    float acc = h0 * w0.x + h1 * w0.y + h2 * w0.z + h3 * w0.w
              + h4 * w1.x + h5 * w1.y + h6 * w1.z + h7 * w1.w;
#pragma unroll
    for (int off = 1; off < 32; off <<= 1)
      acc += __shfl_xor(acc, off, 64);
    if (l32 == 0) out[e] = acc + bias;
  }
}

extern "C" void kernel_launch(void* const* d_in, const int* in_sizes, int n_in,
                              void* d_out, int out_size, void* d_ws, size_t ws_size,
                              hipStream_t stream) {
  const float* E   = (const float*)d_in[0];
  const int*   idx = (const int*)d_in[1];
  const float* W1  = (const float*)d_in[2];
  const float* b1  = (const float*)d_in[3];
  const float* W2  = (const float*)d_in[4];
  const float* b2  = (const float*)d_in[5];
  float* out = (float*)d_out;

  char* ws = (char*)d_ws;
  unsigned short* Wtf = (unsigned short*)ws;                        // 256 KiB
  unsigned short* P   = (unsigned short*)(ws + 262144);             // 48.83 MiB
  int* ctl  = (int*)(ws + 262144 + 51200000);                       // 12 ints
  int* perm = (int*)(ws + 262144 + 51200000 + 256);                 // 1.2 MB

  hipLaunchKernelGGL(pack_w_kernel, dim3(HID), dim3(128), 0, stream, W1, Wtf, ctl);
  hipLaunchKernelGGL(hist_kernel, dim3(512), dim3(256), 0, stream, idx, ctl);
  hipLaunchKernelGGL(scan_kernel, dim3(1), dim3(64), 0, stream, ctl);
  hipLaunchKernelGGL(scatter_kernel, dim3(512), dim3(256), 0, stream, idx, ctl, perm);
  hipLaunchKernelGGL(gemm_kernel, dim3(256), dim3(512), 0, stream, E, Wtf, b1, P);
  // Gray-code class order AA(0) -> AB(1) -> BB(3) -> BA(2): consecutive launches
  // share one 12.8MB P-half in the shared TCC.
  const int order[4] = {0, 1, 3, 2};
  for (int k = 0; k < 4; ++k)
    hipLaunchKernelGGL(edge_kernel, dim3(1024), dim3(256), 0, stream,
                       idx, perm, ctl, order[k], P, W2, b2, out);
}

// Round 7
// 96.840 us; speedup vs baseline: 3.4351x; 3.4351x over previous
//
#include <hip/hip_runtime.h>
#include <hip/hip_bf16.h>

#define N_NODES 50000
#define HID     256
#define N_EDGES 300000
#define NT      32   // nodes per GEMM tile
#define NTILES  ((N_NODES + NT - 1) / NT)

typedef __attribute__((ext_vector_type(8))) short bf16x8;
typedef __attribute__((ext_vector_type(4))) float f32x4;

__device__ __forceinline__ unsigned short f2bf(float f) {
  unsigned int u = __float_as_uint(f);
  u = (u + 0x7FFFu + ((u >> 16) & 1u)) >> 16;   // RNE
  return (unsigned short)u;
}
__device__ __forceinline__ float bflo(unsigned int u) { return __uint_as_float(u << 16); }
__device__ __forceinline__ float bfhi(unsigned int u) { return __uint_as_float(u & 0xFFFF0000u); }

__device__ __forceinline__ bf16x8 cvt8(float4 u, float4 v) {
  bf16x8 r;
  r[0] = (short)f2bf(u.x); r[1] = (short)f2bf(u.y);
  r[2] = (short)f2bf(u.z); r[3] = (short)f2bf(u.w);
  r[4] = (short)f2bf(v.x); r[5] = (short)f2bf(v.y);
  r[6] = (short)f2bf(v.z); r[7] = (short)f2bf(v.w);
  return r;
}

struct StageRegs { float4 a, b, c, d; };

__device__ __forceinline__ void load_tile(const float* __restrict__ E, int tile,
                                          int srow, int sg, StageRegs& s) {
  int grow = tile * NT + srow;
  if (grow < N_NODES) {
    const float4* p = reinterpret_cast<const float4*>(E + (size_t)grow * HID + sg * 8);
    s.a = p[0]; s.b = p[1]; s.c = p[32]; s.d = p[33];
  } else {
    s.a = s.b = s.c = s.d = make_float4(0.f, 0.f, 0.f, 0.f);
  }
}

// ---- kernel 1: Wcat^T in MFMA-fragment order (coalesced reads).
__global__ __launch_bounds__(128) void pack_w_kernel(
    const float* __restrict__ W1, unsigned short* __restrict__ Wtf) {
  int k = blockIdx.x;          // 0..255
  int t = threadIdx.x;         // 0..127
  int half = t >> 6;
  int jj = (t & 63) * 4;
  const float4 v = *reinterpret_cast<const float4*>(
      W1 + (size_t)(half ? (HID + k) : k) * HID + jj);
  float vv[4] = {v.x, v.y, v.z, v.w};
#pragma unroll
  for (int e = 0; e < 4; ++e) {
    int j = half * HID + jj + e;
    int f    = (j >> 4) * 8 + (k >> 5);
    int lane = (j & 15) | (((k >> 3) & 3) << 4);
    int elem = k & 7;
    Wtf[f * 512 + lane * 8 + elem] = f2bf(vv[e]);
  }
}

// ---- kernel 2: weights-stationary streaming GEMM, depth-2 prefetch.
// Output layout (region-blocked for the 2-pass edge gather):
//   P0[n][0:128]=PS[n][0:128], P0[n][128:256]=PT[n][0:128]   (25.6 MB)
//   P1[n][0:128]=PS[n][128:256], P1[n][128:256]=PT[n][128:256]
__global__ __launch_bounds__(512, 2) void gemm_kernel(
    const float* __restrict__ E, const unsigned short* __restrict__ Wtf,
    const float* __restrict__ b1, unsigned short* __restrict__ P) {
  __shared__ alignas(16) char lds0[16384];   // 32 rows x 512B bf16, XOR-swizzled
  __shared__ alignas(16) char lds1[16384];
  const int tid  = threadIdx.x;
  const int lane = tid & 63;
  const int w    = tid >> 6;                 // 0..7

  bf16x8 a[4][8];
#pragma unroll
  for (int m = 0; m < 4; ++m)
#pragma unroll
    for (int kk = 0; kk < 8; ++kk)
      a[m][kk] = *reinterpret_cast<const bf16x8*>(
          Wtf + (((size_t)(w * 4 + m) * 8 + kk) << 9) + lane * 8);

  float4 bv[4];
#pragma unroll
  for (int m = 0; m < 4; ++m) {
    int fm = w * 4 + m;
    bv[m] = (fm < 16) ? *reinterpret_cast<const float4*>(b1 + fm * 16 + ((lane >> 4) << 2))
                      : make_float4(0.f, 0.f, 0.f, 0.f);
  }

  const int srow = tid >> 4;               // 0..31
  const int sg   = tid & 15;
  const int woff0 = srow * 512 + ((sg * 16) ^ ((srow & 7) << 4));
  const int woff1 = srow * 512 + (((sg + 16) * 16) ^ ((srow & 7) << 4));
  const int G = gridDim.x;

  auto write_tile = [&](char* buf, const StageRegs& s) {
    *reinterpret_cast<bf16x8*>(&buf[woff0]) = cvt8(s.a, s.b);
    *reinterpret_cast<bf16x8*>(&buf[woff1]) = cvt8(s.c, s.d);
  };

  auto compute_store = [&](const char* buf, int tt) {
    f32x4 acc[4][2] = {};
#pragma unroll
    for (int n = 0; n < 2; ++n) {
      int r   = n * 16 + (lane & 15);
      int rb  = r * 512;
      int sw  = (r & 7) << 4;
      int kb0 = (lane >> 4) << 4;
      bf16x8 bfr[8];
#pragma unroll
      for (int kk = 0; kk < 8; ++kk)
        bfr[kk] = *reinterpret_cast<const bf16x8*>(&buf[rb + ((kk * 64 + kb0) ^ sw)]);
#pragma unroll
      for (int kk = 0; kk < 8; ++kk)
#pragma unroll
        for (int m = 0; m < 4; ++m)
          acc[m][n] = __builtin_amdgcn_mfma_f32_16x16x32_bf16(a[m][kk], bfr[kk], acc[m][n], 0, 0, 0);
    }
#pragma unroll
    for (int m = 0; m < 4; ++m) {
      int j0 = (w * 4 + m) * 16 + ((lane >> 4) << 2);       // logical Pcat col base
      int region   = (j0 >> 7) & 1;                          // hidden-half block
      int elem_off = ((j0 >> 8) << 7) + (j0 & 127);          // src/trg | col-in-half
      size_t rbase = (size_t)region * ((size_t)N_NODES * 256);
#pragma unroll
      for (int n = 0; n < 2; ++n) {
        int node = tt * NT + n * 16 + (lane & 15);
        if (node < N_NODES) {
          ushort4 o;
          o.x = f2bf(acc[m][n][0] + bv[m].x);
          o.y = f2bf(acc[m][n][1] + bv[m].y);
          o.z = f2bf(acc[m][n][2] + bv[m].z);
          o.w = f2bf(acc[m][n][3] + bv[m].w);
          *reinterpret_cast<ushort4*>(P + rbase + (size_t)node * 256 + elem_off) = o;
        }
      }
    }
  };

  int t = blockIdx.x;
  StageRegs sX, sY;
  load_tile(E, t, srow, sg, sX);
  if (t + G < NTILES) load_tile(E, t + G, srow, sg, sY);
  write_tile(lds0, sX);
  if (t + 2 * G < NTILES) load_tile(E, t + 2 * G, srow, sg, sX);
  __syncthreads();

  while (true) {
    compute_store(lds0, t);
    if (t + G >= NTILES) break;
    write_tile(lds1, sY);
    if (t + 3 * G < NTILES) load_tile(E, t + 3 * G, srow, sg, sY);
    __syncthreads();
    t += G;
    compute_store(lds1, t);
    if (t + G >= NTILES) break;
    write_tile(lds0, sX);
    if (t + 3 * G < NTILES) load_tile(E, t + 3 * G, srow, sg, sX);
    __syncthreads();
    t += G;
  }
}

// ---- kernel 3: hidden-split edge pass. Pass p gathers only region Pp (25.6 MB,
// TCC-resident). 1 edge per 32-lane half; lane loads 4 bf16 of PS[s] and PT[t].
// pass 0: part[e] = dot; pass 1: out[e] = dot + part[e] + bias.
__global__ __launch_bounds__(256) void edge_pass_kernel(
    const int* __restrict__ idx, const unsigned short* __restrict__ Pp,
    const float* __restrict__ W2seg, const float* __restrict__ b2,
    float* __restrict__ part, float* __restrict__ out, int pass) {
  const int tid  = threadIdx.x;
  const int lane = tid & 63;
  const int l32  = lane & 31;
  const int half = lane >> 5;
  const int wv     = blockIdx.x * 4 + (tid >> 6);
  const int nwaves = gridDim.x * 4;
  const float4 w2 = *reinterpret_cast<const float4*>(W2seg + l32 * 4);
  const float bias = b2[0];
  for (int ep = wv; ep < N_EDGES / 2; ep += nwaves) {
    int e = ep * 2 + half;
    int s = idx[e];
    int t = idx[N_EDGES + e];
    uint2 ua = *reinterpret_cast<const uint2*>(Pp + (size_t)s * 256 + l32 * 4);
    uint2 ub = *reinterpret_cast<const uint2*>(Pp + (size_t)t * 256 + 128 + l32 * 4);
    float h0 = fmaxf(bflo(ua.x) + bflo(ub.x), 0.f);
    float h1 = fmaxf(bfhi(ua.x) + bfhi(ub.x), 0.f);
    float h2 = fmaxf(bflo(ua.y) + bflo(ub.y), 0.f);
    float h3 = fmaxf(bfhi(ua.y) + bfhi(ub.y), 0.f);
    float acc = h0 * w2.x + h1 * w2.y + h2 * w2.z + h3 * w2.w;
#pragma unroll
    for (int off = 1; off < 32; off <<= 1)
      acc += __shfl_xor(acc, off, 64);   // stays within each 32-lane half
    if (l32 == 0) {
      if (pass == 0) part[e] = acc;
      else           out[e]  = acc + part[e] + bias;
    }
  }
}

extern "C" void kernel_launch(void* const* d_in, const int* in_sizes, int n_in,
                              void* d_out, int out_size, void* d_ws, size_t ws_size,
                              hipStream_t stream) {
  const float* E   = (const float*)d_in[0];
  const int*   idx = (const int*)d_in[1];
  const float* W1  = (const float*)d_in[2];
  const float* b1  = (const float*)d_in[3];
  const float* W2  = (const float*)d_in[4];
  const float* b2  = (const float*)d_in[5];
  float* out = (float*)d_out;

  char* ws = (char*)d_ws;
  unsigned short* Wtf = (unsigned short*)ws;                 // 256 KiB
  unsigned short* P   = (unsigned short*)(ws + 262144);      // 2 x 25.6 MB regions
  float* part = (float*)(ws + 262144 + 51200000);            // 1.2 MB fp32 partials

  hipLaunchKernelGGL(pack_w_kernel, dim3(HID), dim3(128), 0, stream, W1, Wtf);
  hipLaunchKernelGGL(gemm_kernel, dim3(256), dim3(512), 0, stream, E, Wtf, b1, P);
  hipLaunchKernelGGL(edge_pass_kernel, dim3(2048), dim3(256), 0, stream,
                     idx, P, W2, b2, part, out, 0);
  hipLaunchKernelGGL(edge_pass_kernel, dim3(2048), dim3(256), 0, stream,
                     idx, P + (size_t)N_NODES * 256, W2 + 128, b2, part, out, 1);
}

// Round 8
// 83.138 us; speedup vs baseline: 4.0012x; 1.1648x over previous
//
#include <hip/hip_runtime.h>
#include <hip/hip_bf16.h>

#define N_NODES 50000
#define HID     256
#define N_EDGES 300000
#define NT      32   // nodes per GEMM tile
#define NTILES  ((N_NODES + NT - 1) / NT)

typedef __attribute__((ext_vector_type(8))) short bf16x8;
typedef __attribute__((ext_vector_type(4))) float f32x4;

__device__ __forceinline__ unsigned short f2bf(float f) {
  unsigned int u = __float_as_uint(f);
  u = (u + 0x7FFFu + ((u >> 16) & 1u)) >> 16;   // RNE
  return (unsigned short)u;
}
__device__ __forceinline__ float bflo(unsigned int u) { return __uint_as_float(u << 16); }
__device__ __forceinline__ float bfhi(unsigned int u) { return __uint_as_float(u & 0xFFFF0000u); }

__device__ __forceinline__ bf16x8 cvt8(float4 u, float4 v) {
  bf16x8 r;
  r[0] = (short)f2bf(u.x); r[1] = (short)f2bf(u.y);
  r[2] = (short)f2bf(u.z); r[3] = (short)f2bf(u.w);
  r[4] = (short)f2bf(v.x); r[5] = (short)f2bf(v.y);
  r[6] = (short)f2bf(v.z); r[7] = (short)f2bf(v.w);
  return r;
}

struct StageRegs { float4 a, b; };

// ---- kernel 1: Wcat^T in MFMA-fragment order (coalesced reads).
__global__ __launch_bounds__(128) void pack_w_kernel(
    const float* __restrict__ W1, unsigned short* __restrict__ Wtf) {
  int k = blockIdx.x;          // 0..255
  int t = threadIdx.x;         // 0..127
  int half = t >> 6;
  int jj = (t & 63) * 4;
  const float4 v = *reinterpret_cast<const float4*>(
      W1 + (size_t)(half ? (HID + k) : k) * HID + jj);
  float vv[4] = {v.x, v.y, v.z, v.w};
#pragma unroll
  for (int e = 0; e < 4; ++e) {
    int j = half * HID + jj + e;
    int f    = (j >> 4) * 8 + (k >> 5);
    int lane = (j & 15) | (((k >> 3) & 3) << 4);
    int elem = k & 7;
    Wtf[f * 512 + lane * 8 + elem] = f2bf(vv[e]);
  }
}

// ---- kernel 2: weights-stationary streaming GEMM, depth-2 prefetch.
// 16 waves x 32 P-cols each (A = 64 VGPR/wave) -> ~120 VGPR total -> 4 waves/SIMD.
__global__ __launch_bounds__(1024, 4) void gemm_kernel(
    const float* __restrict__ E, const unsigned short* __restrict__ Wtf,
    const float* __restrict__ b1, unsigned short* __restrict__ P) {
  __shared__ alignas(16) char lds0[16384];   // 32 rows x 512B bf16, XOR-swizzled
  __shared__ alignas(16) char lds1[16384];
  const int tid  = threadIdx.x;
  const int lane = tid & 63;
  const int w    = tid >> 6;                 // 0..15

  // persistent A fragments: wave w owns P-cols [w*32, w*32+32) x K=256 (64 VGPR)
  bf16x8 a[2][8];
#pragma unroll
  for (int m = 0; m < 2; ++m)
#pragma unroll
    for (int kk = 0; kk < 8; ++kk)
      a[m][kk] = *reinterpret_cast<const bf16x8*>(
          Wtf + (((size_t)(w * 2 + m) * 8 + kk) << 9) + lane * 8);

  float4 bv[2];
#pragma unroll
  for (int m = 0; m < 2; ++m) {
    int fm = w * 2 + m;
    bv[m] = (fm < 16) ? *reinterpret_cast<const float4*>(b1 + fm * 16 + ((lane >> 4) << 2))
                      : make_float4(0.f, 0.f, 0.f, 0.f);
  }

  // staging: 1024 threads, one 16B bf16 granule each (32 rows x 32 granules)
  const int srow = tid >> 5;               // 0..31
  const int sg   = tid & 31;               // granule in row
  const int woff = srow * 512 + ((sg * 16) ^ ((srow & 7) << 4));
  const int G = gridDim.x;

  auto load_tile = [&](int tile, StageRegs& s) {
    int grow = tile * NT + srow;
    if (grow < N_NODES) {
      const float4* p = reinterpret_cast<const float4*>(E + (size_t)grow * HID + sg * 8);
      s.a = p[0]; s.b = p[1];
    } else {
      s.a = s.b = make_float4(0.f, 0.f, 0.f, 0.f);
    }
  };
  auto write_tile = [&](char* buf, const StageRegs& s) {
    *reinterpret_cast<bf16x8*>(&buf[woff]) = cvt8(s.a, s.b);
  };

  auto compute_store = [&](const char* buf, int tt) {
    f32x4 acc[2][2] = {};
#pragma unroll
    for (int n = 0; n < 2; ++n) {
      int r   = n * 16 + (lane & 15);
      int rb  = r * 512;
      int sw  = (r & 7) << 4;
      int kb0 = (lane >> 4) << 4;
      bf16x8 bfr[8];
#pragma unroll
      for (int kk = 0; kk < 8; ++kk)
        bfr[kk] = *reinterpret_cast<const bf16x8*>(&buf[rb + ((kk * 64 + kb0) ^ sw)]);
#pragma unroll
      for (int kk = 0; kk < 8; ++kk)
#pragma unroll
        for (int m = 0; m < 2; ++m)
          acc[m][n] = __builtin_amdgcn_mfma_f32_16x16x32_bf16(a[m][kk], bfr[kk], acc[m][n], 0, 0, 0);
    }
#pragma unroll
    for (int m = 0; m < 2; ++m) {
      int pcb = (w * 2 + m) * 16 + ((lane >> 4) << 2);
#pragma unroll
      for (int n = 0; n < 2; ++n) {
        int node = tt * NT + n * 16 + (lane & 15);
        if (node < N_NODES) {
          ushort4 o;
          o.x = f2bf(acc[m][n][0] + bv[m].x);
          o.y = f2bf(acc[m][n][1] + bv[m].y);
          o.z = f2bf(acc[m][n][2] + bv[m].z);
          o.w = f2bf(acc[m][n][3] + bv[m].w);
          *reinterpret_cast<ushort4*>(P + (size_t)node * 512 + pcb) = o;
        }
      }
    }
  };

  int t = blockIdx.x;
  StageRegs sX, sY;
  // prologue: lds0 <- tile t; sY <- t+G; sX <- t+2G (depth-2 in flight)
  load_tile(t, sX);
  if (t + G < NTILES) load_tile(t + G, sY);
  write_tile(lds0, sX);
  if (t + 2 * G < NTILES) load_tile(t + 2 * G, sX);
  __syncthreads();

  while (true) {
    compute_store(lds0, t);
    if (t + G >= NTILES) break;
    write_tile(lds1, sY);
    if (t + 3 * G < NTILES) load_tile(t + 3 * G, sY);
    __syncthreads();
    t += G;
    compute_store(lds1, t);
    if (t + G >= NTILES) break;
    write_tile(lds0, sX);
    if (t + 3 * G < NTILES) load_tile(t + 3 * G, sX);
    __syncthreads();
    t += G;
  }
}

// ---- kernel 3: 2 edges per wave (32 lanes each), 16B bf16x8 gathers (round-4 proven).
__global__ __launch_bounds__(256) void edge_kernel(
    const int* __restrict__ idx, const unsigned short* __restrict__ P,
    const float* __restrict__ W2, const float* __restrict__ b2,
    float* __restrict__ out) {
  const int tid  = threadIdx.x;
  const int lane = tid & 63;
  const int l32  = lane & 31;
  const int half = lane >> 5;
  const int wv     = blockIdx.x * 4 + (tid >> 6);
  const int nwaves = gridDim.x * 4;
  const float4 w0 = *reinterpret_cast<const float4*>(W2 + l32 * 8);
  const float4 w1 = *reinterpret_cast<const float4*>(W2 + l32 * 8 + 4);
  const float bias = b2[0];
  for (int ep = wv; ep < N_EDGES / 2; ep += nwaves) {
    int e = ep * 2 + half;
    int s = idx[e];
    int t = idx[N_EDGES + e];
    uint4 ua = *reinterpret_cast<const uint4*>(P + (size_t)s * 512 + l32 * 8);
    uint4 ub = *reinterpret_cast<const uint4*>(P + (size_t)t * 512 + 256 + l32 * 8);
    float h0 = fmaxf(bflo(ua.x) + bflo(ub.x), 0.f);
    float h1 = fmaxf(bfhi(ua.x) + bfhi(ub.x), 0.f);
    float h2 = fmaxf(bflo(ua.y) + bflo(ub.y), 0.f);
    float h3 = fmaxf(bfhi(ua.y) + bfhi(ub.y), 0.f);
    float h4 = fmaxf(bflo(ua.z) + bflo(ub.z), 0.f);
    float h5 = fmaxf(bfhi(ua.z) + bfhi(ub.z), 0.f);
    float h6 = fmaxf(bflo(ua.w) + bflo(ub.w), 0.f);
    float h7 = fmaxf(bfhi(ua.w) + bfhi(ub.w), 0.f);
    float acc = h0 * w0.x + h1 * w0.y + h2 * w0.z + h3 * w0.w
              + h4 * w1.x + h5 * w1.y + h6 * w1.z + h7 * w1.w;
#pragma unroll
    for (int off = 1; off < 32; off <<= 1)
      acc += __shfl_xor(acc, off, 64);   // stays within each 32-lane half
    if (l32 == 0) out[e] = acc + bias;
  }
}

extern "C" void kernel_launch(void* const* d_in, const int* in_sizes, int n_in,
                              void* d_out, int out_size, void* d_ws, size_t ws_size,
                              hipStream_t stream) {
  const float* E   = (const float*)d_in[0];
  const int*   idx = (const int*)d_in[1];
  const float* W1  = (const float*)d_in[2];
  const float* b1  = (const float*)d_in[3];
  const float* W2  = (const float*)d_in[4];
  const float* b2  = (const float*)d_in[5];
  float* out = (float*)d_out;

  unsigned short* Wtf = (unsigned short*)d_ws;                 // 256 KiB
  unsigned short* P   = (unsigned short*)((char*)d_ws + 262144); // 48.83 MiB

  hipLaunchKernelGGL(pack_w_kernel, dim3(HID), dim3(128), 0, stream, W1, Wtf);
  hipLaunchKernelGGL(gemm_kernel, dim3(256), dim3(1024), 0, stream, E, Wtf, b1, P);
  hipLaunchKernelGGL(edge_kernel, dim3(2048), dim3(256), 0, stream, idx, P, W2, b2, out);
}